// Round 2
// baseline (2185.636 us; speedup 1.0000x reference)
//
#include <hip/hip_runtime.h>
#include <hip/hip_bf16.h>
#include <math.h>

// Problem constants (match reference)
#define N_PIX   262144
#define G_NUM   4096
#define K_FREQ  4
#define GSTRIDE 32      // floats per packed gaussian record (128 B)
#define TG      128     // gaussians per LDS tile (16 KB)
#define BLOCK   256
#define PPT     2       // pixels per thread (packed as float2 lanes)

typedef float v2f __attribute__((ext_vector_type(2)));

__device__ __forceinline__ v2f splat2(float f) { v2f r; r.x = f; r.y = f; return r; }
__device__ __forceinline__ v2f pkfma(v2f a, v2f b, v2f c) {
    return __builtin_elementwise_fma(a, b, c);
}

#if __has_builtin(__builtin_amdgcn_exp2f)
#define EXP2F(x) __builtin_amdgcn_exp2f(x)
#else
#define EXP2F(x) exp2f(x)
#endif

// acc += c * cos(2*pi * t * f), evaluated for a pixel-pair packed in v2f.
// Range-reduce r = v - rint(v) in [-0.5,0.5] (v_rndne, exact), then even
// Taylor poly deg-14: max err ~4.3e-6.
__device__ __forceinline__ v2f cosacc(v2f t, float f, float c, v2f acc) {
    v2f v = t * splat2(f);
    v2f R; R.x = __builtin_rintf(v.x); R.y = __builtin_rintf(v.y);
    v2f r = v - R;
    v2f z = r * r;
    v2f p = splat2(-1.7143914f);
    p = pkfma(z, p, splat2(  7.9035360f));
    p = pkfma(z, p, splat2(-26.4262640f));
    p = pkfma(z, p, splat2( 60.2446414f));
    p = pkfma(z, p, splat2(-85.4568172f));
    p = pkfma(z, p, splat2( 64.9393940f));
    p = pkfma(z, p, splat2(-19.7392088f));
    p = pkfma(z, p, splat2(  1.0f));
    return pkfma(p, splat2(c), acc);
}

// Pack per-gaussian params into a 32-float record:
// [0..3]  px, py, cos(rot), sin(rot)
// [4..7]  isx*S, isy*S, color0, color1      (S = sqrt(0.5*log2(e)))
// [8]     color2
// [12..15] fx[0..3]  [16..19] cx[0..3]  [20..23] fy[0..3]  [24..27] cy[0..3]
__global__ void prep_kernel(const float* __restrict__ colors,
                            const float* __restrict__ pos,
                            const float* __restrict__ scales,
                            const float* __restrict__ rots,
                            const float* __restrict__ coeffs,
                            const int*   __restrict__ idx,
                            float* __restrict__ gp)
{
    int g = blockIdx.x * blockDim.x + threadIdx.x;
    if (g >= G_NUM) return;
    float sr, cr;
    sincosf(rots[g], &sr, &cr);
    const float SC = 0.84932180028801904f;   // sqrt(0.5 * log2(e))
    float isx = expf(scales[2*g + 0]) * SC;
    float isy = expf(scales[2*g + 1]) * SC;
    float* o = gp + (size_t)g * GSTRIDE;
    o[0] = pos[2*g];  o[1] = pos[2*g + 1];  o[2] = cr;  o[3] = sr;
    o[4] = isx;       o[5] = isy;
    o[6] = colors[3*g];  o[7] = colors[3*g + 1];
    o[8] = colors[3*g + 2];  o[9] = 0.f;  o[10] = 0.f;  o[11] = 0.f;
    const float FS = 1024.0f / 1024.0f;   // MAXF / NF
#pragma unroll
    for (int k = 0; k < K_FREQ; ++k) {
        o[12 + k] = (float)idx[g*2*K_FREQ + 2*k + 0] * FS;
        o[16 + k] = coeffs[g*2*K_FREQ + 2*k + 0];
        o[20 + k] = (float)idx[g*2*K_FREQ + 2*k + 1] * FS;
        o[24 + k] = coeffs[g*2*K_FREQ + 2*k + 1];
    }
    o[28] = 0.f; o[29] = 0.f; o[30] = 0.f; o[31] = 0.f;
}

__global__ __launch_bounds__(BLOCK) void render_kernel(
    const float* __restrict__ x,
    const float* __restrict__ gp,
    float* __restrict__ out)
{
    __shared__ __align__(16) float sg[TG * GSTRIDE];
    const int tid  = threadIdx.x;
    const int pix0 = blockIdx.x * (BLOCK * PPT) + tid;   // second pixel: pix0 + BLOCK

    const float2* __restrict__ x2 = (const float2*)x;
    const float2 P0 = x2[pix0];
    const float2 P1 = x2[pix0 + BLOCK];
    v2f Px; Px.x = P0.x; Px.y = P1.x;
    v2f Py; Py.x = P0.y; Py.y = P1.y;

    v2f ar = splat2(0.f), ag = splat2(0.f), ab = splat2(0.f);

    for (int base = 0; base < G_NUM; base += TG) {
        __syncthreads();
        {   // cooperative stage: TG*32 floats = 1024 float4, 4 per thread
            const float4* __restrict__ src = (const float4*)(gp + (size_t)base * GSTRIDE);
            float4* dst = (float4*)sg;
#pragma unroll
            for (int j = 0; j < (TG * GSTRIDE / 4) / BLOCK; ++j)
                dst[tid + j * BLOCK] = src[tid + j * BLOCK];
        }
        __syncthreads();

        for (int t = 0; t < TG; ++t) {
            const float* q = sg + t * GSTRIDE;
            const float4 A  = *(const float4*)(q + 0);    // px, py, cr, sr
            const float4 Bv = *(const float4*)(q + 4);    // isx, isy, c0, c1
            const float  c2 = q[8];
            const float4 FX = *(const float4*)(q + 12);
            const float4 CX = *(const float4*)(q + 16);
            const float4 FY = *(const float4*)(q + 20);
            const float4 CY = *(const float4*)(q + 24);

            v2f dx = Px - splat2(A.x);
            v2f dy = Py - splat2(A.y);
            v2f tx = pkfma(dy, splat2(A.w), dx * splat2(A.z));
            v2f ty = pkfma(dx, splat2(-A.w), dy * splat2(A.z));
            v2f bx = tx * splat2(Bv.x);
            v2f by = ty * splat2(Bv.y);
            v2f ga = pkfma(by, by, bx * bx);
            v2f gw; gw.x = EXP2F(-ga.x); gw.y = EXP2F(-ga.y);

            v2f wx = splat2(0.f);
            wx = cosacc(tx, FX.x, CX.x, wx);
            wx = cosacc(tx, FX.y, CX.y, wx);
            wx = cosacc(tx, FX.z, CX.z, wx);
            wx = cosacc(tx, FX.w, CX.w, wx);

            v2f wy = splat2(0.f);
            wy = cosacc(ty, FY.x, CY.x, wy);
            wy = cosacc(ty, FY.y, CY.y, wy);
            wy = cosacc(ty, FY.z, CY.z, wy);
            wy = cosacc(ty, FY.w, CY.w, wy);

            v2f w = (gw * wx) * wy;
            ar = pkfma(w, splat2(Bv.z), ar);
            ag = pkfma(w, splat2(Bv.w), ag);
            ab = pkfma(w, splat2(c2), ab);
        }
    }

    const int o0 = pix0 * 3;
    out[o0 + 0] = ar.x; out[o0 + 1] = ag.x; out[o0 + 2] = ab.x;
    const int o1 = (pix0 + BLOCK) * 3;
    out[o1 + 0] = ar.y; out[o1 + 1] = ag.y; out[o1 + 2] = ab.y;
}

extern "C" void kernel_launch(void* const* d_in, const int* in_sizes, int n_in,
                              void* d_out, int out_size, void* d_ws, size_t ws_size,
                              hipStream_t stream) {
    const float* x      = (const float*)d_in[0];   // [N,2]
    const float* colors = (const float*)d_in[1];   // [G,3]
    const float* pos    = (const float*)d_in[2];   // [G,2]
    const float* scales = (const float*)d_in[3];   // [G,2]
    const float* rots   = (const float*)d_in[4];   // [G,1]
    const float* coeffs = (const float*)d_in[5];   // [G,K,2]
    const int*   idx    = (const int*)d_in[6];     // [G,K,2]
    float* out = (float*)d_out;
    float* gp  = (float*)d_ws;                     // needs G*32*4 = 512 KB

    prep_kernel<<<(G_NUM + 255) / 256, 256, 0, stream>>>(
        colors, pos, scales, rots, coeffs, idx, gp);
    render_kernel<<<N_PIX / (BLOCK * PPT), BLOCK, 0, stream>>>(x, gp, out);
}

// Round 3
// 1698.204 us; speedup vs baseline: 1.2870x; 1.2870x over previous
//
#include <hip/hip_runtime.h>
#include <hip/hip_bf16.h>
#include <math.h>

// Problem constants (match reference)
#define N_PIX   262144
#define G_NUM   4096
#define K_FREQ  4
#define GSTRIDE 32      // floats per packed gaussian record (128 B)
#define BLOCK   256

#if __has_builtin(__builtin_amdgcn_exp2f)
#define EXP2F(x) __builtin_amdgcn_exp2f(x)
#else
#define EXP2F(x) exp2f(x)
#endif

// cos(2*pi*v): v_cos_f32 takes revolutions; v_fract_f32 does range reduction.
__device__ __forceinline__ float cos2pi(float v) {
    return __builtin_amdgcn_cosf(__builtin_amdgcn_fractf(v));
}

// Pack per-gaussian params into a 32-float record:
// [0..3]  px, py, cos(rot), sin(rot)
// [4..7]  isx*S, isy*S, color0, color1      (S = sqrt(0.5*log2(e)))
// [8]     color2  (rest of that float4 pad)
// [12..15] fx[0..3]  [16..19] cx[0..3]  [20..23] fy[0..3]  [24..27] cy[0..3]
__global__ void prep_kernel(const float* __restrict__ colors,
                            const float* __restrict__ pos,
                            const float* __restrict__ scales,
                            const float* __restrict__ rots,
                            const float* __restrict__ coeffs,
                            const int*   __restrict__ idx,
                            float* __restrict__ gp)
{
    int g = blockIdx.x * blockDim.x + threadIdx.x;
    if (g >= G_NUM) return;
    float sr, cr;
    sincosf(rots[g], &sr, &cr);
    const float SC = 0.84932180028801904f;   // sqrt(0.5 * log2(e))
    float isx = expf(scales[2*g + 0]) * SC;
    float isy = expf(scales[2*g + 1]) * SC;
    float* o = gp + (size_t)g * GSTRIDE;
    o[0] = pos[2*g];  o[1] = pos[2*g + 1];  o[2] = cr;  o[3] = sr;
    o[4] = isx;       o[5] = isy;
    o[6] = colors[3*g];  o[7] = colors[3*g + 1];
    o[8] = colors[3*g + 2];  o[9] = 0.f;  o[10] = 0.f;  o[11] = 0.f;
    const float FS = 1024.0f / 1024.0f;   // MAXF / NF
#pragma unroll
    for (int k = 0; k < K_FREQ; ++k) {
        o[12 + k] = (float)idx[g*2*K_FREQ + 2*k + 0] * FS;
        o[16 + k] = coeffs[g*2*K_FREQ + 2*k + 0];
        o[20 + k] = (float)idx[g*2*K_FREQ + 2*k + 1] * FS;
        o[24 + k] = coeffs[g*2*K_FREQ + 2*k + 1];
    }
    o[28] = 0.f; o[29] = 0.f; o[30] = 0.f; o[31] = 0.f;
}

// One pixel per thread; gaussian params read at a wave-uniform address each
// iteration -> scalar (s_load) path, no LDS, no barriers. 4096 waves =
// 4 waves/SIMD.
__global__ __launch_bounds__(BLOCK) void render_kernel(
    const float* __restrict__ x,
    const float* __restrict__ gp,
    float* __restrict__ out)
{
    const int pix = blockIdx.x * BLOCK + threadIdx.x;
    const float2 P = ((const float2*)x)[pix];

    float ar = 0.f, ag = 0.f, ab = 0.f;

    const float4* __restrict__ q4 = (const float4*)gp;

#pragma unroll 2
    for (int t = 0; t < G_NUM; ++t) {
        const float4* q = q4 + t * (GSTRIDE / 4);
        const float4 A  = q[0];          // px, py, cr, sr
        const float4 Bv = q[1];          // isx', isy', c0, c1
        const float  c2 = q[2].x;
        const float4 FX = q[3];
        const float4 CX = q[4];
        const float4 FY = q[5];
        const float4 CY = q[6];

        float dx = P.x - A.x, dy = P.y - A.y;
        float tx = fmaf(dy,  A.w, dx * A.z);
        float ty = fmaf(dx, -A.w, dy * A.z);
        float bx = tx * Bv.x, by = ty * Bv.y;
        float ga = fmaf(by, by, bx * bx);       // (scaled) quadratic form
        float gw = EXP2F(-ga);

        float wx;
        wx  = CX.x * cos2pi(tx * FX.x);
        wx  = fmaf(CX.y, cos2pi(tx * FX.y), wx);
        wx  = fmaf(CX.z, cos2pi(tx * FX.z), wx);
        wx  = fmaf(CX.w, cos2pi(tx * FX.w), wx);
        float wy;
        wy  = CY.x * cos2pi(ty * FY.x);
        wy  = fmaf(CY.y, cos2pi(ty * FY.y), wy);
        wy  = fmaf(CY.z, cos2pi(ty * FY.z), wy);
        wy  = fmaf(CY.w, cos2pi(ty * FY.w), wy);

        float w = (gw * wx) * wy;
        ar = fmaf(w, Bv.z, ar);
        ag = fmaf(w, Bv.w, ag);
        ab = fmaf(w, c2,  ab);
    }

    const int o = pix * 3;
    out[o + 0] = ar; out[o + 1] = ag; out[o + 2] = ab;
}

extern "C" void kernel_launch(void* const* d_in, const int* in_sizes, int n_in,
                              void* d_out, int out_size, void* d_ws, size_t ws_size,
                              hipStream_t stream) {
    const float* x      = (const float*)d_in[0];   // [N,2]
    const float* colors = (const float*)d_in[1];   // [G,3]
    const float* pos    = (const float*)d_in[2];   // [G,2]
    const float* scales = (const float*)d_in[3];   // [G,2]
    const float* rots   = (const float*)d_in[4];   // [G,1]
    const float* coeffs = (const float*)d_in[5];   // [G,K,2]
    const int*   idx    = (const int*)d_in[6];     // [G,K,2]
    float* out = (float*)d_out;
    float* gp  = (float*)d_ws;                     // needs G*32*4 = 512 KB

    prep_kernel<<<(G_NUM + 255) / 256, 256, 0, stream>>>(
        colors, pos, scales, rots, coeffs, idx, gp);
    render_kernel<<<N_PIX / BLOCK, BLOCK, 0, stream>>>(x, gp, out);
}

// Round 4
// 1576.777 us; speedup vs baseline: 1.3861x; 1.0770x over previous
//
#include <hip/hip_runtime.h>
#include <hip/hip_bf16.h>
#include <math.h>

// Problem constants (match reference)
#define N_PIX   262144
#define G_NUM   4096
#define K_FREQ  4
#define GSTRIDE 32      // floats per packed gaussian record (128 B)
#define BLOCK   256
#define GSPLIT  2       // gaussian-range split: doubles wave count for occupancy

#if __has_builtin(__builtin_amdgcn_exp2f)
#define EXP2F(x) __builtin_amdgcn_exp2f(x)
#else
#define EXP2F(x) exp2f(x)
#endif

// cos(2*pi*v): v_cos_f32 takes revolutions; v_fract_f32 does range reduction.
__device__ __forceinline__ float cos2pi(float v) {
    return __builtin_amdgcn_cosf(__builtin_amdgcn_fractf(v));
}

// Pack per-gaussian params into a 32-float record:
// [0..3]  px, py, cos(rot), sin(rot)
// [4..7]  isx*S, isy*S, color0, color1      (S = sqrt(0.5*log2(e)))
// [8]     color2
// [12..15] fx[0..3]  [16..19] cx[0..3]  [20..23] fy[0..3]  [24..27] cy[0..3]
__global__ void prep_kernel(const float* __restrict__ colors,
                            const float* __restrict__ pos,
                            const float* __restrict__ scales,
                            const float* __restrict__ rots,
                            const float* __restrict__ coeffs,
                            const int*   __restrict__ idx,
                            float* __restrict__ gp)
{
    int g = blockIdx.x * blockDim.x + threadIdx.x;
    if (g >= G_NUM) return;
    float sr, cr;
    sincosf(rots[g], &sr, &cr);
    const float SC = 0.84932180028801904f;   // sqrt(0.5 * log2(e))
    float isx = expf(scales[2*g + 0]) * SC;
    float isy = expf(scales[2*g + 1]) * SC;
    float* o = gp + (size_t)g * GSTRIDE;
    o[0] = pos[2*g];  o[1] = pos[2*g + 1];  o[2] = cr;  o[3] = sr;
    o[4] = isx;       o[5] = isy;
    o[6] = colors[3*g];  o[7] = colors[3*g + 1];
    o[8] = colors[3*g + 2];  o[9] = 0.f;  o[10] = 0.f;  o[11] = 0.f;
    const float FS = 1024.0f / 1024.0f;   // MAXF / NF
#pragma unroll
    for (int k = 0; k < K_FREQ; ++k) {
        o[12 + k] = (float)idx[g*2*K_FREQ + 2*k + 0] * FS;
        o[16 + k] = coeffs[g*2*K_FREQ + 2*k + 0];
        o[20 + k] = (float)idx[g*2*K_FREQ + 2*k + 1] * FS;
        o[24 + k] = coeffs[g*2*K_FREQ + 2*k + 1];
    }
    o[28] = 0.f; o[29] = 0.f; o[30] = 0.f; o[31] = 0.f;
}

// One pixel per thread over a G_NUM/GSPLIT gaussian range; params read at
// wave-uniform addresses -> SGPRs via s_load (VGPR=16, SGPR=80 measured).
// blockIdx.y selects the gaussian half; partial RGB accumulated to d_out
// with atomicAdd (d_out zeroed on stream before launch).
__global__ __launch_bounds__(BLOCK) void render_kernel(
    const float* __restrict__ x,
    const float* __restrict__ gp,
    float* __restrict__ out)
{
    const int pix = blockIdx.x * BLOCK + threadIdx.x;
    const float2 P = ((const float2*)x)[pix];

    float ar = 0.f, ag = 0.f, ab = 0.f;

    const int g0 = blockIdx.y * (G_NUM / GSPLIT);
    const float4* __restrict__ q4 = (const float4*)gp + (size_t)g0 * (GSTRIDE / 4);

#pragma unroll 2
    for (int t = 0; t < G_NUM / GSPLIT; ++t) {
        const float4* q = q4 + t * (GSTRIDE / 4);
        const float4 A  = q[0];          // px, py, cr, sr
        const float4 Bv = q[1];          // isx', isy', c0, c1
        const float  c2 = q[2].x;
        const float4 FX = q[3];
        const float4 CX = q[4];
        const float4 FY = q[5];
        const float4 CY = q[6];

        float dx = P.x - A.x, dy = P.y - A.y;
        float tx = fmaf(dy,  A.w, dx * A.z);
        float ty = fmaf(dx, -A.w, dy * A.z);
        float bx = tx * Bv.x, by = ty * Bv.y;
        float ga = fmaf(by, by, bx * bx);
        float gw = EXP2F(-ga);

        float wx;
        wx  = CX.x * cos2pi(tx * FX.x);
        wx  = fmaf(CX.y, cos2pi(tx * FX.y), wx);
        wx  = fmaf(CX.z, cos2pi(tx * FX.z), wx);
        wx  = fmaf(CX.w, cos2pi(tx * FX.w), wx);
        float wy;
        wy  = CY.x * cos2pi(ty * FY.x);
        wy  = fmaf(CY.y, cos2pi(ty * FY.y), wy);
        wy  = fmaf(CY.z, cos2pi(ty * FY.z), wy);
        wy  = fmaf(CY.w, cos2pi(ty * FY.w), wy);

        float w = (gw * wx) * wy;
        ar = fmaf(w, Bv.z, ar);
        ag = fmaf(w, Bv.w, ag);
        ab = fmaf(w, c2,  ab);
    }

    const int o = pix * 3;
    atomicAdd(&out[o + 0], ar);
    atomicAdd(&out[o + 1], ag);
    atomicAdd(&out[o + 2], ab);
}

extern "C" void kernel_launch(void* const* d_in, const int* in_sizes, int n_in,
                              void* d_out, int out_size, void* d_ws, size_t ws_size,
                              hipStream_t stream) {
    const float* x      = (const float*)d_in[0];   // [N,2]
    const float* colors = (const float*)d_in[1];   // [G,3]
    const float* pos    = (const float*)d_in[2];   // [G,2]
    const float* scales = (const float*)d_in[3];   // [G,2]
    const float* rots   = (const float*)d_in[4];   // [G,1]
    const float* coeffs = (const float*)d_in[5];   // [G,K,2]
    const int*   idx    = (const int*)d_in[6];     // [G,K,2]
    float* out = (float*)d_out;
    float* gp  = (float*)d_ws;                     // needs G*32*4 = 512 KB

    prep_kernel<<<(G_NUM + 255) / 256, 256, 0, stream>>>(
        colors, pos, scales, rots, coeffs, idx, gp);

    hipMemsetAsync(out, 0, (size_t)out_size * sizeof(float), stream);

    dim3 grid(N_PIX / BLOCK, GSPLIT);
    render_kernel<<<grid, BLOCK, 0, stream>>>(x, gp, out);
}